// Round 12
// baseline (252.198 us; speedup 1.0000x reference)
//
#include <hip/hip_runtime.h>

typedef unsigned int u32;
typedef unsigned short u16;
typedef unsigned long long u64;

typedef __attribute__((ext_vector_type(8))) short s8v;       // 8 bf16 (4 VGPRs)
typedef __attribute__((ext_vector_type(4))) float f4v;       // 4 fp32 acc
typedef __attribute__((ext_vector_type(8))) _Float16 h8v;    // 8 fp16 = 16 B

#define B_SZ   8192
#define V_SZ   1000
#define KCH    5
#define MAXDEG 32

__device__ __forceinline__ u16 f2bf(float f) {
    u32 u = __float_as_uint(f);
    u32 r = (u + 0x7FFFu + ((u >> 16) & 1u)) >> 16;   // RNE
    return (u16)r;
}
__device__ __forceinline__ float bf2f(u16 h) { return __uint_as_float(((u32)h) << 16); }

// ---------------------------------------------------------------------------
// K0: fused prep = {sparse build of Lr} U {weight bf16 conversion + BN fold}.
// blocks 0..249: build (wave-per-row scan of dense L), blocks 250..889: conv.
// Split sparse layout: wts[q4*V+v][4] fp32, colsu[q4*V+v][4] u16 (transposed,
// coalesced in k_cheby). Tails zero-padded (col 0, weight 0).
// ---------------------------------------------------------------------------
__global__ __launch_bounds__(256) void k_prep(const float* __restrict__ L,
                                              const float* __restrict__ lmax,
                                              float* __restrict__ wts,
                                              u16* __restrict__ colsu,
                                              int* __restrict__ cnts,
                                              float* __restrict__ diagw,
                                              const float* __restrict__ fc1W,
                                              const float* __restrict__ lin1W,
                                              const float* __restrict__ gam,
                                              const float* __restrict__ bet,
                                              const float* __restrict__ mea,
                                              const float* __restrict__ var,
                                              u16* __restrict__ fc1w_b,
                                              u16* __restrict__ lin1w_b,
                                              float* __restrict__ bn_a,
                                              float* __restrict__ bn_c) {
    if (blockIdx.x < 250) {
        int wid  = threadIdx.x >> 6;
        int lane = threadIdx.x & 63;
        int row  = blockIdx.x * 4 + wid;
        if (row >= V_SZ) return;
        float s = 2.0f / lmax[0];
        const float* Lrow = L + (u64)row * V_SZ;
        int cnt = 0;
        for (int c0 = 0; c0 < V_SZ; c0 += 64) {
            int c = c0 + lane;
            float val = 0.0f;
            if (c < V_SZ && c != row) val = Lrow[c];
            bool nz = (val != 0.0f);
            u64 m = __ballot(nz);
            int pos = cnt + __popcll(m & ((1ull << lane) - 1ull));
            if (nz && pos < MAXDEG) {
                int idx = ((pos >> 2) * V_SZ + row) * 4 + (pos & 3);
                wts[idx]   = val * s;
                colsu[idx] = (u16)c;
            }
            cnt += __popcll(m);
        }
        int cc = cnt < MAXDEG ? cnt : MAXDEG;
        for (int e = cc + lane; e < MAXDEG; e += 64) {
            int idx = ((e >> 2) * V_SZ + row) * 4 + (e & 3);
            wts[idx]   = 0.0f;
            colsu[idx] = 0;
        }
        if (lane == 0) {
            cnts[row]  = cc;
            diagw[row] = s * Lrow[row] - 1.0f;
        }
    } else {
        int t = (blockIdx.x - 250) * 256 + threadIdx.x;
        if (t < 256 * 640) {
            int r = t / 640, c = t - r * 640;
            fc1w_b[t] = (c < 625) ? f2bf(fc1W[r * 625 + c]) : (u16)0;
        }
        if (t < 256 * 256) lin1w_b[t] = f2bf(lin1W[t]);
        if (t < 4 * 256) {
            float a = gam[t] * rsqrtf(var[t] + 1e-5f);
            bn_a[t] = a;
            bn_c[t] = bet[t] - mea[t] * a;
        }
    }
}

// ---------------------------------------------------------------------------
// K1: fused Chebyshev recursion + cl1 + ReLU + maxpool8 -> bf16.
// 1024 thr, 1 row/thread, 8 batch cols/block. FP16 LDS stage buffers (r12):
// one h8v row slot = 16 B -> each neighbor gather is ONE ds_read_b128 (was 2)
// -> LDS pipe work halves (the measured bottleneck). Own-row recursion path
// (diag, 2y - x_{k-2}, feat accum) stays fp32 in registers; only gathered
// neighbor values are fp16-rounded (est +0.01 absmax; fp16 not bf16 for the
// 10-bit mantissa). Row stride 16 B -> bank group 4v%32 -> v%8 spread (same
// as proven float4 layout). LDS 32.2 KB -> occupancy no longer LDS-capped.
// ---------------------------------------------------------------------------
__global__ __launch_bounds__(1024) void k_cheby(const float* __restrict__ x,
                                                const float4* __restrict__ wts4,
                                                const uint2* __restrict__ cols2,
                                                const int* __restrict__ cnts,
                                                const float* __restrict__ diagw,
                                                const float* __restrict__ cl1W,
                                                const float* __restrict__ cl1b,
                                                u16* __restrict__ pooled) {
    __shared__ __align__(16) h8v hbuf[2][V_SZ];   // pingpong, 8 cols fp16 = 32 KB
    __shared__ float cws[25];
    __shared__ float cbs[5];
    int t  = threadIdx.x;
    int b0 = blockIdx.x * 8;

    if (t < 25) cws[t] = cl1W[t];
    if (t < 5)  cbs[t] = cl1b[t];

    const bool own = (t < V_SZ);
    const int  tc  = own ? t : (V_SZ - 1);    // clamped for structure loads

    float d0 = own ? diagw[tc] : 0.0f;
    int   n0 = own ? ((cnts[tc] + 3) >> 2) : 0;

    // stage-0 staging; own values kept in fp32 registers
    float4 pm1l = make_float4(0.f, 0.f, 0.f, 0.f), pm1h = pm1l, pm2l, pm2h;
    if (own) {
        pm1l.x = x[(u64)(b0 + 0) * V_SZ + t];
        pm1l.y = x[(u64)(b0 + 1) * V_SZ + t];
        pm1l.z = x[(u64)(b0 + 2) * V_SZ + t];
        pm1l.w = x[(u64)(b0 + 3) * V_SZ + t];
        pm1h.x = x[(u64)(b0 + 4) * V_SZ + t];
        pm1h.y = x[(u64)(b0 + 5) * V_SZ + t];
        pm1h.z = x[(u64)(b0 + 6) * V_SZ + t];
        pm1h.w = x[(u64)(b0 + 7) * V_SZ + t];
        h8v hv;
        hv[0] = (_Float16)pm1l.x; hv[1] = (_Float16)pm1l.y;
        hv[2] = (_Float16)pm1l.z; hv[3] = (_Float16)pm1l.w;
        hv[4] = (_Float16)pm1h.x; hv[5] = (_Float16)pm1h.y;
        hv[6] = (_Float16)pm1h.z; hv[7] = (_Float16)pm1h.w;
        hbuf[0][t] = hv;
    }
    pm2l = pm1l; pm2h = pm1h;
    __syncthreads();

    // feat init with k=0 term
    float4 fl[5], fh[5];
#pragma unroll
    for (int f = 0; f < 5; ++f) {
        float w = cws[f * 5];
        fl[f] = make_float4(w * pm1l.x, w * pm1l.y, w * pm1l.z, w * pm1l.w);
        fh[f] = make_float4(w * pm1h.x, w * pm1h.y, w * pm1h.z, w * pm1h.w);
    }

    // stages 1..4
#pragma unroll
    for (int k = 1; k < KCH; ++k) {
        const h8v* prevb = hbuf[(k - 1) & 1];
        h8v*       curb  = hbuf[k & 1];

        if (own) {
            float4 al = make_float4(d0 * pm1l.x, d0 * pm1l.y, d0 * pm1l.z, d0 * pm1l.w);
            float4 ah = make_float4(d0 * pm1h.x, d0 * pm1h.y, d0 * pm1h.z, d0 * pm1h.w);
            float4 wq = wts4[tc];
            uint2  cq = cols2[tc];
            for (int q = 0; q < n0; ++q) {
                float4 wqn = wq;
                uint2  cqn = cq;
                if (q + 1 < n0) {
                    wqn = wts4[(q + 1) * V_SZ + tc];      // coalesced
                    cqn = cols2[(q + 1) * V_SZ + tc];
                }
                u32 c0i = cq.x & 0xFFFFu, c1i = cq.x >> 16;
                u32 c2i = cq.y & 0xFFFFu, c3i = cq.y >> 16;
                h8v g0 = prevb[c0i];
                h8v g1 = prevb[c1i];
                h8v g2 = prevb[c2i];
                h8v g3 = prevb[c3i];
                al.x = fmaf(wq.x, (float)g0[0], al.x); al.y = fmaf(wq.x, (float)g0[1], al.y);
                al.z = fmaf(wq.x, (float)g0[2], al.z); al.w = fmaf(wq.x, (float)g0[3], al.w);
                ah.x = fmaf(wq.x, (float)g0[4], ah.x); ah.y = fmaf(wq.x, (float)g0[5], ah.y);
                ah.z = fmaf(wq.x, (float)g0[6], ah.z); ah.w = fmaf(wq.x, (float)g0[7], ah.w);
                al.x = fmaf(wq.y, (float)g1[0], al.x); al.y = fmaf(wq.y, (float)g1[1], al.y);
                al.z = fmaf(wq.y, (float)g1[2], al.z); al.w = fmaf(wq.y, (float)g1[3], al.w);
                ah.x = fmaf(wq.y, (float)g1[4], ah.x); ah.y = fmaf(wq.y, (float)g1[5], ah.y);
                ah.z = fmaf(wq.y, (float)g1[6], ah.z); ah.w = fmaf(wq.y, (float)g1[7], ah.w);
                al.x = fmaf(wq.z, (float)g2[0], al.x); al.y = fmaf(wq.z, (float)g2[1], al.y);
                al.z = fmaf(wq.z, (float)g2[2], al.z); al.w = fmaf(wq.z, (float)g2[3], al.w);
                ah.x = fmaf(wq.z, (float)g2[4], ah.x); ah.y = fmaf(wq.z, (float)g2[5], ah.y);
                ah.z = fmaf(wq.z, (float)g2[6], ah.z); ah.w = fmaf(wq.z, (float)g2[7], ah.w);
                al.x = fmaf(wq.w, (float)g3[0], al.x); al.y = fmaf(wq.w, (float)g3[1], al.y);
                al.z = fmaf(wq.w, (float)g3[2], al.z); al.w = fmaf(wq.w, (float)g3[3], al.w);
                ah.x = fmaf(wq.w, (float)g3[4], ah.x); ah.y = fmaf(wq.w, (float)g3[5], ah.y);
                ah.z = fmaf(wq.w, (float)g3[6], ah.z); ah.w = fmaf(wq.w, (float)g3[7], ah.w);
                wq = wqn; cq = cqn;
            }
            if (k >= 2) {
                al.x = fmaf(2.0f, al.x, -pm2l.x); al.y = fmaf(2.0f, al.y, -pm2l.y);
                al.z = fmaf(2.0f, al.z, -pm2l.z); al.w = fmaf(2.0f, al.w, -pm2l.w);
                ah.x = fmaf(2.0f, ah.x, -pm2h.x); ah.y = fmaf(2.0f, ah.y, -pm2h.y);
                ah.z = fmaf(2.0f, ah.z, -pm2h.z); ah.w = fmaf(2.0f, ah.w, -pm2h.w);
            }
            h8v hv;
            hv[0] = (_Float16)al.x; hv[1] = (_Float16)al.y;
            hv[2] = (_Float16)al.z; hv[3] = (_Float16)al.w;
            hv[4] = (_Float16)ah.x; hv[5] = (_Float16)ah.y;
            hv[6] = (_Float16)ah.z; hv[7] = (_Float16)ah.w;
            curb[t] = hv;
            pm2l = pm1l; pm2h = pm1h;
            pm1l = al;   pm1h = ah;
#pragma unroll
            for (int f = 0; f < 5; ++f) {
                float w = cws[f * 5 + k];
                fl[f].x = fmaf(w, al.x, fl[f].x); fl[f].y = fmaf(w, al.y, fl[f].y);
                fl[f].z = fmaf(w, al.z, fl[f].z); fl[f].w = fmaf(w, al.w, fl[f].w);
                fh[f].x = fmaf(w, ah.x, fh[f].x); fh[f].y = fmaf(w, ah.y, fh[f].y);
                fh[f].z = fmaf(w, ah.z, fh[f].z); fh[f].w = fmaf(w, ah.w, fh[f].w);
            }
        }
        __syncthreads();
    }

    // bias + ReLU + maxpool8 via 8-lane shuffle (8 consecutive t = 8 consecutive v)
#pragma unroll
    for (int f = 0; f < 5; ++f) {
#pragma unroll
        for (int b = 0; b < 8; ++b) {
            float c0 = (b == 0) ? fl[f].x : (b == 1) ? fl[f].y
                     : (b == 2) ? fl[f].z : (b == 3) ? fl[f].w
                     : (b == 4) ? fh[f].x : (b == 5) ? fh[f].y
                     : (b == 6) ? fh[f].z : fh[f].w;
            float s = own ? fmaxf(c0 + cbs[f], 0.0f) : 0.0f;
            s = fmaxf(s, __shfl_xor(s, 1));
            s = fmaxf(s, __shfl_xor(s, 2));
            s = fmaxf(s, __shfl_xor(s, 4));
            if ((t & 7) == 0 && own)
                pooled[(u64)(b0 + b) * 640 + (t >> 3) * 5 + f] = f2bf(s);
        }
    }
    // zero the K-padding columns 625..639 for the 8 batch rows
    if (t < 120) {
        int b = t / 15, c = 625 + (t % 15);
        pooled[(u64)(b0 + b) * 640 + c] = 0;
    }
}

// ---------------------------------------------------------------------------
// K2: fused tail (round-7 proven). One block = 64 batch rows end-to-end:
//   z  = JKmax(BNx4(relu-chain)) of (pooled[64,640] @ fc1W^T + b)   -> LDS
//   z2 = relu(z @ lin1W^T + b1)                                    -> LDS
//   out= log_softmax(z2 @ l2W^T + b2)                              -> global
// Bs indices TILE-RELATIVE, zs ABSOLUTE (round-6 NaN bug).
// ---------------------------------------------------------------------------
__global__ __launch_bounds__(256) void k_tail(const u16* __restrict__ A,      // pooled [B,640]
                                              const u16* __restrict__ W0,     // fc1w_b [256,640]
                                              const float* __restrict__ b0v,  // fc1b
                                              const float* __restrict__ bn_a,
                                              const float* __restrict__ bn_c,
                                              const u16* __restrict__ W1,     // lin1w_b [256,256]
                                              const float* __restrict__ b1v,  // lin1b
                                              const float* __restrict__ W2,   // l2W [10,256] f32
                                              const float* __restrict__ b2v,  // l2b
                                              float* __restrict__ out) {
    __shared__ u16   As[64][72];
    __shared__ u16   Bs[256][72];
    __shared__ u16   zs[64][264];
    __shared__ float w2s[2560];
    __shared__ float b2s[10];
    int t    = threadIdx.x;
    int lane = t & 63;
    int wid  = t >> 6;
    int r0   = blockIdx.x * 64;

    for (int c = t; c < 2560; c += 256) w2s[c] = W2[c];
    if (t < 10) b2s[t] = b2v[t];

    f4v acc[16];
#pragma unroll
    for (int j = 0; j < 16; ++j) acc[j] = (f4v){0.f, 0.f, 0.f, 0.f};

    // ---------------- phase A: z = pooled @ W0^T (K=640) ----------------
    for (int k0 = 0; k0 < 640; k0 += 64) {
        int4 ra[2], rb[8];
#pragma unroll
        for (int i = 0; i < 2; ++i) {
            int c = t + i * 256, row = c >> 3, kc = c & 7;
            ra[i] = *(const int4*)(A + (u64)(r0 + row) * 640 + k0 + kc * 8);
        }
#pragma unroll
        for (int i = 0; i < 8; ++i) {
            int c = t + i * 256, row = c >> 3, kc = c & 7;
            rb[i] = *(const int4*)(W0 + (u64)row * 640 + k0 + kc * 8);
        }
        __syncthreads();
#pragma unroll
        for (int i = 0; i < 2; ++i) {
            int c = t + i * 256, row = c >> 3, kc = c & 7;
            *(int4*)(&As[row][kc * 8]) = ra[i];
        }
#pragma unroll
        for (int i = 0; i < 8; ++i) {
            int c = t + i * 256, row = c >> 3, kc = c & 7;
            *(int4*)(&Bs[row][kc * 8]) = rb[i];
        }
        __syncthreads();
#pragma unroll
        for (int ks = 0; ks < 2; ++ks) {
            int kq = ks * 32 + (lane >> 4) * 8;
            s8v af = *(const s8v*)(&As[wid * 16 + (lane & 15)][kq]);
#pragma unroll
            for (int nt = 0; nt < 16; ++nt) {
                s8v bf = *(const s8v*)(&Bs[nt * 16 + (lane & 15)][kq]);
                acc[nt] = __builtin_amdgcn_mfma_f32_16x16x32_bf16(af, bf, acc[nt], 0, 0, 0);
            }
        }
    }
#pragma unroll
    for (int nt = 0; nt < 16; ++nt) {
        int col = nt * 16 + (lane & 15);
        float bv = b0v[col];
        float a_[4], c_[4];
#pragma unroll
        for (int i = 0; i < 4; ++i) {
            a_[i] = bn_a[i * 256 + col];
            c_[i] = bn_c[i * 256 + col];
        }
        int rb_ = wid * 16 + (lane >> 4) * 4;
#pragma unroll
        for (int r = 0; r < 4; ++r) {
            float h = acc[nt][r] + bv, z = 0.0f;
#pragma unroll
            for (int i = 0; i < 4; ++i) {
                h = fmaxf(fmaf(a_[i], h, c_[i]), 0.0f);
                z = fmaxf(z, h);
            }
            zs[rb_ + r][col] = f2bf(z);
        }
    }
    __syncthreads();

    // ---------------- phase B: z2 = relu(z @ W1^T + b1) (K=256) ----------
#pragma unroll
    for (int j = 0; j < 16; ++j) acc[j] = (f4v){0.f, 0.f, 0.f, 0.f};
    for (int k0 = 0; k0 < 256; k0 += 64) {
        int4 rb[8];
#pragma unroll
        for (int i = 0; i < 8; ++i) {
            int c = t + i * 256, row = c >> 3, kc = c & 7;
            rb[i] = *(const int4*)(W1 + (u64)row * 256 + k0 + kc * 8);
        }
        __syncthreads();
#pragma unroll
        for (int i = 0; i < 8; ++i) {
            int c = t + i * 256, row = c >> 3, kc = c & 7;
            *(int4*)(&Bs[row][kc * 8]) = rb[i];
        }
        __syncthreads();
#pragma unroll
        for (int ks = 0; ks < 2; ++ks) {
            int kqr = ks * 32 + (lane >> 4) * 8;        // tile-relative: Bs
            s8v af = *(const s8v*)(&zs[wid * 16 + (lane & 15)][k0 + kqr]);  // absolute: zs
#pragma unroll
            for (int nt = 0; nt < 16; ++nt) {
                s8v bf = *(const s8v*)(&Bs[nt * 16 + (lane & 15)][kqr]);
                acc[nt] = __builtin_amdgcn_mfma_f32_16x16x32_bf16(af, bf, acc[nt], 0, 0, 0);
            }
        }
    }
#pragma unroll
    for (int nt = 0; nt < 16; ++nt) {
        int col = nt * 16 + (lane & 15);
        float bv = b1v[col];
        int rb_ = wid * 16 + (lane >> 4) * 4;
#pragma unroll
        for (int r = 0; r < 4; ++r)
            zs[rb_ + r][col] = f2bf(fmaxf(acc[nt][r] + bv, 0.0f));
    }
    __syncthreads();

    // ---------------- phase C: lin2 + log_softmax ------------------------
    {
        int row = t >> 2, sub = t & 3;
        float a10[10];
#pragma unroll
        for (int o = 0; o < 10; ++o) a10[o] = 0.0f;
        const u32* zrow = (const u32*)(&zs[row][0]);
        for (int kk = sub * 32; kk < sub * 32 + 32; ++kk) {
            u32 pz = zrow[kk];
            float z0 = bf2f((u16)(pz & 0xFFFFu));
            float z1 = bf2f((u16)(pz >> 16));
#pragma unroll
            for (int o = 0; o < 10; ++o) {
                a10[o] = fmaf(z0, w2s[o * 256 + kk * 2], a10[o]);
                a10[o] = fmaf(z1, w2s[o * 256 + kk * 2 + 1], a10[o]);
            }
        }
#pragma unroll
        for (int o = 0; o < 10; ++o) {
            a10[o] += __shfl_xor(a10[o], 1);
            a10[o] += __shfl_xor(a10[o], 2);
        }
        if (sub == 0) {
            float l[10], mx = -1e30f;
#pragma unroll
            for (int o = 0; o < 10; ++o) { l[o] = a10[o] + b2s[o]; mx = fmaxf(mx, l[o]); }
            float s = 0.0f;
#pragma unroll
            for (int o = 0; o < 10; ++o) s += expf(l[o] - mx);
            float ls = logf(s);
            float* orow = out + (u64)(r0 + row) * 10;
#pragma unroll
            for (int o = 0; o < 10; ++o) orow[o] = l[o] - mx - ls;
        }
    }
}

// ---------------------------------------------------------------------------
extern "C" void kernel_launch(void* const* d_in, const int* in_sizes, int n_in,
                              void* d_out, int out_size, void* d_ws, size_t ws_size,
                              hipStream_t stream) {
    const float* x    = (const float*)d_in[0];
    const float* L    = (const float*)d_in[1];
    const float* lmax = (const float*)d_in[2];
    const float* cl1W = (const float*)d_in[3];
    const float* cl1b = (const float*)d_in[4];
    const float* fc1W = (const float*)d_in[5];
    const float* fc1b = (const float*)d_in[6];
    const float* gam  = (const float*)d_in[7];
    const float* bet  = (const float*)d_in[8];
    const float* mea  = (const float*)d_in[9];
    const float* var  = (const float*)d_in[10];
    const float* l1W  = (const float*)d_in[11];
    const float* l1b  = (const float*)d_in[12];
    const float* l2W  = (const float*)d_in[13];
    const float* l2b  = (const float*)d_in[14];

    char* ws = (char*)d_ws;
    float* wts     = (float*)(ws + 0);        // 131072 (8*1000*4 f32)
    u16*   colsu   = (u16*)(ws + 131072);     // 65536  (8*1000*4 u16)
    int*   cnts    = (int*)(ws + 196608);     // 4096
    float* diagw   = (float*)(ws + 200704);   // 4096
    float* bn_a    = (float*)(ws + 204800);   // 4096
    float* bn_c    = (float*)(ws + 208896);   // 4096
    u16*   fc1w_b  = (u16*)(ws + 212992);     // 327680
    u16*   lin1w_b = (u16*)(ws + 540672);     // 131072
    u16*   pooled  = (u16*)(ws + 671744);     // 10485760 (total ~11.2 MB)
    float* outp    = (float*)d_out;

    k_prep<<<dim3(890), dim3(256), 0, stream>>>(L, lmax, wts, colsu, cnts, diagw,
                                                fc1W, l1W, gam, bet, mea, var,
                                                fc1w_b, lin1w_b, bn_a, bn_c);
    k_cheby<<<dim3(1024), dim3(1024), 0, stream>>>(x, (const float4*)wts,
                                                   (const uint2*)colsu, cnts, diagw,
                                                   cl1W, cl1b, pooled);
    k_tail<<<dim3(128), dim3(256), 0, stream>>>(pooled, fc1w_b, fc1b, bn_a, bn_c,
                                                lin1w_b, l1b, l2W, l2b, outp);
}

// Round 13
// 232.806 us; speedup vs baseline: 1.0833x; 1.0833x over previous
//
#include <hip/hip_runtime.h>

typedef unsigned int u32;
typedef unsigned short u16;
typedef unsigned long long u64;

typedef __attribute__((ext_vector_type(8))) short s8v;       // 8 bf16 (4 VGPRs)
typedef __attribute__((ext_vector_type(4))) float f4v;       // 4 fp32 acc
typedef __attribute__((ext_vector_type(8))) _Float16 h8v;    // 8 fp16 = 16 B

#define B_SZ   8192
#define V_SZ   1000
#define KCH    5
#define MAXDEG 32

__device__ __forceinline__ u16 f2bf(float f) {
    u32 u = __float_as_uint(f);
    u32 r = (u + 0x7FFFu + ((u >> 16) & 1u)) >> 16;   // RNE
    return (u16)r;
}
__device__ __forceinline__ float bf2f(u16 h) { return __uint_as_float(((u32)h) << 16); }

// acc += w * fp16(lo/hi half of h2) in ONE v_fma_mix_f32 (r12's compiler
// output was scalar v_cvt_f32_f16 + v_fma_f32 -> VALU 44->60%; this removes it)
__device__ __forceinline__ float fmix_lo(float acc, float w, u32 h2) {
    asm("v_fma_mix_f32 %0, %1, %2, %0 op_sel_hi:[0,1,0]"
        : "+v"(acc) : "v"(w), "v"(h2));
    return acc;
}
__device__ __forceinline__ float fmix_hi(float acc, float w, u32 h2) {
    asm("v_fma_mix_f32 %0, %1, %2, %0 op_sel:[0,1,0] op_sel_hi:[0,1,0]"
        : "+v"(acc) : "v"(w), "v"(h2));
    return acc;
}

// ---------------------------------------------------------------------------
// K0: fused prep = {sparse build of Lr} U {weight bf16 conversion + BN fold}.
// blocks 0..249: build (wave-per-row scan of dense L), blocks 250..889: conv.
// Split sparse layout: wts[q4*V+v][4] fp32, colsu[q4*V+v][4] u16 (transposed,
// coalesced in k_cheby). Tails zero-padded (col 0, weight 0).
// ---------------------------------------------------------------------------
__global__ __launch_bounds__(256) void k_prep(const float* __restrict__ L,
                                              const float* __restrict__ lmax,
                                              float* __restrict__ wts,
                                              u16* __restrict__ colsu,
                                              int* __restrict__ cnts,
                                              float* __restrict__ diagw,
                                              const float* __restrict__ fc1W,
                                              const float* __restrict__ lin1W,
                                              const float* __restrict__ gam,
                                              const float* __restrict__ bet,
                                              const float* __restrict__ mea,
                                              const float* __restrict__ var,
                                              u16* __restrict__ fc1w_b,
                                              u16* __restrict__ lin1w_b,
                                              float* __restrict__ bn_a,
                                              float* __restrict__ bn_c) {
    if (blockIdx.x < 250) {
        int wid  = threadIdx.x >> 6;
        int lane = threadIdx.x & 63;
        int row  = blockIdx.x * 4 + wid;
        if (row >= V_SZ) return;
        float s = 2.0f / lmax[0];
        const float* Lrow = L + (u64)row * V_SZ;
        int cnt = 0;
        for (int c0 = 0; c0 < V_SZ; c0 += 64) {
            int c = c0 + lane;
            float val = 0.0f;
            if (c < V_SZ && c != row) val = Lrow[c];
            bool nz = (val != 0.0f);
            u64 m = __ballot(nz);
            int pos = cnt + __popcll(m & ((1ull << lane) - 1ull));
            if (nz && pos < MAXDEG) {
                int idx = ((pos >> 2) * V_SZ + row) * 4 + (pos & 3);
                wts[idx]   = val * s;
                colsu[idx] = (u16)c;
            }
            cnt += __popcll(m);
        }
        int cc = cnt < MAXDEG ? cnt : MAXDEG;
        for (int e = cc + lane; e < MAXDEG; e += 64) {
            int idx = ((e >> 2) * V_SZ + row) * 4 + (e & 3);
            wts[idx]   = 0.0f;
            colsu[idx] = 0;
        }
        if (lane == 0) {
            cnts[row]  = cc;
            diagw[row] = s * Lrow[row] - 1.0f;
        }
    } else {
        int t = (blockIdx.x - 250) * 256 + threadIdx.x;
        if (t < 256 * 640) {
            int r = t / 640, c = t - r * 640;
            fc1w_b[t] = (c < 625) ? f2bf(fc1W[r * 625 + c]) : (u16)0;
        }
        if (t < 256 * 256) lin1w_b[t] = f2bf(lin1W[t]);
        if (t < 4 * 256) {
            float a = gam[t] * rsqrtf(var[t] + 1e-5f);
            bn_a[t] = a;
            bn_c[t] = bet[t] - mea[t] * a;
        }
    }
}

// ---------------------------------------------------------------------------
// K1: fused Chebyshev recursion + cl1 + ReLU + maxpool8 -> bf16.
// 1024 thr, 1 row/thread, 8 batch cols/block. FP16 LDS stage buffers:
// one row slot = 16 B -> one ds_read_b128 per neighbor gather, and each
// gathered element feeds ONE v_fma_mix_f32 (fp32 acc, fp16 src1 via op_sel).
// Own-row recursion path (diag, 2y-x_{k-2}, feat) stays fp32 in registers.
// Row stride 16 B -> bank group 4v%32 -> v%8 spread; conflicts ~5.3e6 (r12).
// ---------------------------------------------------------------------------
__global__ __launch_bounds__(1024) void k_cheby(const float* __restrict__ x,
                                                const float4* __restrict__ wts4,
                                                const uint2* __restrict__ cols2,
                                                const int* __restrict__ cnts,
                                                const float* __restrict__ diagw,
                                                const float* __restrict__ cl1W,
                                                const float* __restrict__ cl1b,
                                                u16* __restrict__ pooled) {
    __shared__ __align__(16) h8v hbuf[2][V_SZ];   // pingpong, 8 cols fp16 = 32 KB
    __shared__ float cws[25];
    __shared__ float cbs[5];
    int t  = threadIdx.x;
    int b0 = blockIdx.x * 8;

    if (t < 25) cws[t] = cl1W[t];
    if (t < 5)  cbs[t] = cl1b[t];

    const bool own = (t < V_SZ);
    const int  tc  = own ? t : (V_SZ - 1);    // clamped for structure loads

    float d0 = own ? diagw[tc] : 0.0f;
    int   n0 = own ? ((cnts[tc] + 3) >> 2) : 0;

    // stage-0 staging; own values kept in fp32 registers
    float4 pm1l = make_float4(0.f, 0.f, 0.f, 0.f), pm1h = pm1l, pm2l, pm2h;
    if (own) {
        pm1l.x = x[(u64)(b0 + 0) * V_SZ + t];
        pm1l.y = x[(u64)(b0 + 1) * V_SZ + t];
        pm1l.z = x[(u64)(b0 + 2) * V_SZ + t];
        pm1l.w = x[(u64)(b0 + 3) * V_SZ + t];
        pm1h.x = x[(u64)(b0 + 4) * V_SZ + t];
        pm1h.y = x[(u64)(b0 + 5) * V_SZ + t];
        pm1h.z = x[(u64)(b0 + 6) * V_SZ + t];
        pm1h.w = x[(u64)(b0 + 7) * V_SZ + t];
        h8v hv;
        hv[0] = (_Float16)pm1l.x; hv[1] = (_Float16)pm1l.y;
        hv[2] = (_Float16)pm1l.z; hv[3] = (_Float16)pm1l.w;
        hv[4] = (_Float16)pm1h.x; hv[5] = (_Float16)pm1h.y;
        hv[6] = (_Float16)pm1h.z; hv[7] = (_Float16)pm1h.w;
        hbuf[0][t] = hv;
    }
    pm2l = pm1l; pm2h = pm1h;
    __syncthreads();

    // feat init with k=0 term
    float4 fl[5], fh[5];
#pragma unroll
    for (int f = 0; f < 5; ++f) {
        float w = cws[f * 5];
        fl[f] = make_float4(w * pm1l.x, w * pm1l.y, w * pm1l.z, w * pm1l.w);
        fh[f] = make_float4(w * pm1h.x, w * pm1h.y, w * pm1h.z, w * pm1h.w);
    }

    // stages 1..4
#pragma unroll
    for (int k = 1; k < KCH; ++k) {
        const uint4* prevb = (const uint4*)hbuf[(k - 1) & 1];
        h8v*         curb  = hbuf[k & 1];

        if (own) {
            float4 al = make_float4(d0 * pm1l.x, d0 * pm1l.y, d0 * pm1l.z, d0 * pm1l.w);
            float4 ah = make_float4(d0 * pm1h.x, d0 * pm1h.y, d0 * pm1h.z, d0 * pm1h.w);
            float4 wq = wts4[tc];
            uint2  cq = cols2[tc];
            for (int q = 0; q < n0; ++q) {
                float4 wqn = wq;
                uint2  cqn = cq;
                if (q + 1 < n0) {
                    wqn = wts4[(q + 1) * V_SZ + tc];      // coalesced
                    cqn = cols2[(q + 1) * V_SZ + tc];
                }
                u32 c0i = cq.x & 0xFFFFu, c1i = cq.x >> 16;
                u32 c2i = cq.y & 0xFFFFu, c3i = cq.y >> 16;
                uint4 g0 = prevb[c0i];
                uint4 g1 = prevb[c1i];
                uint4 g2 = prevb[c2i];
                uint4 g3 = prevb[c3i];
                // word.x = cols 0,1 ; word.y = cols 2,3 ; word.z = 4,5 ; word.w = 6,7
                al.x = fmix_lo(al.x, wq.x, g0.x); al.y = fmix_hi(al.y, wq.x, g0.x);
                al.z = fmix_lo(al.z, wq.x, g0.y); al.w = fmix_hi(al.w, wq.x, g0.y);
                ah.x = fmix_lo(ah.x, wq.x, g0.z); ah.y = fmix_hi(ah.y, wq.x, g0.z);
                ah.z = fmix_lo(ah.z, wq.x, g0.w); ah.w = fmix_hi(ah.w, wq.x, g0.w);
                al.x = fmix_lo(al.x, wq.y, g1.x); al.y = fmix_hi(al.y, wq.y, g1.x);
                al.z = fmix_lo(al.z, wq.y, g1.y); al.w = fmix_hi(al.w, wq.y, g1.y);
                ah.x = fmix_lo(ah.x, wq.y, g1.z); ah.y = fmix_hi(ah.y, wq.y, g1.z);
                ah.z = fmix_lo(ah.z, wq.y, g1.w); ah.w = fmix_hi(ah.w, wq.y, g1.w);
                al.x = fmix_lo(al.x, wq.z, g2.x); al.y = fmix_hi(al.y, wq.z, g2.x);
                al.z = fmix_lo(al.z, wq.z, g2.y); al.w = fmix_hi(al.w, wq.z, g2.y);
                ah.x = fmix_lo(ah.x, wq.z, g2.z); ah.y = fmix_hi(ah.y, wq.z, g2.z);
                ah.z = fmix_lo(ah.z, wq.z, g2.w); ah.w = fmix_hi(ah.w, wq.z, g2.w);
                al.x = fmix_lo(al.x, wq.w, g3.x); al.y = fmix_hi(al.y, wq.w, g3.x);
                al.z = fmix_lo(al.z, wq.w, g3.y); al.w = fmix_hi(al.w, wq.w, g3.y);
                ah.x = fmix_lo(ah.x, wq.w, g3.z); ah.y = fmix_hi(ah.y, wq.w, g3.z);
                ah.z = fmix_lo(ah.z, wq.w, g3.w); ah.w = fmix_hi(ah.w, wq.w, g3.w);
                wq = wqn; cq = cqn;
            }
            if (k >= 2) {
                al.x = fmaf(2.0f, al.x, -pm2l.x); al.y = fmaf(2.0f, al.y, -pm2l.y);
                al.z = fmaf(2.0f, al.z, -pm2l.z); al.w = fmaf(2.0f, al.w, -pm2l.w);
                ah.x = fmaf(2.0f, ah.x, -pm2h.x); ah.y = fmaf(2.0f, ah.y, -pm2h.y);
                ah.z = fmaf(2.0f, ah.z, -pm2h.z); ah.w = fmaf(2.0f, ah.w, -pm2h.w);
            }
            h8v hv;
            hv[0] = (_Float16)al.x; hv[1] = (_Float16)al.y;
            hv[2] = (_Float16)al.z; hv[3] = (_Float16)al.w;
            hv[4] = (_Float16)ah.x; hv[5] = (_Float16)ah.y;
            hv[6] = (_Float16)ah.z; hv[7] = (_Float16)ah.w;
            curb[t] = hv;
            pm2l = pm1l; pm2h = pm1h;
            pm1l = al;   pm1h = ah;
#pragma unroll
            for (int f = 0; f < 5; ++f) {
                float w = cws[f * 5 + k];
                fl[f].x = fmaf(w, al.x, fl[f].x); fl[f].y = fmaf(w, al.y, fl[f].y);
                fl[f].z = fmaf(w, al.z, fl[f].z); fl[f].w = fmaf(w, al.w, fl[f].w);
                fh[f].x = fmaf(w, ah.x, fh[f].x); fh[f].y = fmaf(w, ah.y, fh[f].y);
                fh[f].z = fmaf(w, ah.z, fh[f].z); fh[f].w = fmaf(w, ah.w, fh[f].w);
            }
        }
        __syncthreads();
    }

    // bias + ReLU + maxpool8 via 8-lane shuffle (8 consecutive t = 8 consecutive v)
#pragma unroll
    for (int f = 0; f < 5; ++f) {
#pragma unroll
        for (int b = 0; b < 8; ++b) {
            float c0 = (b == 0) ? fl[f].x : (b == 1) ? fl[f].y
                     : (b == 2) ? fl[f].z : (b == 3) ? fl[f].w
                     : (b == 4) ? fh[f].x : (b == 5) ? fh[f].y
                     : (b == 6) ? fh[f].z : fh[f].w;
            float s = own ? fmaxf(c0 + cbs[f], 0.0f) : 0.0f;
            s = fmaxf(s, __shfl_xor(s, 1));
            s = fmaxf(s, __shfl_xor(s, 2));
            s = fmaxf(s, __shfl_xor(s, 4));
            if ((t & 7) == 0 && own)
                pooled[(u64)(b0 + b) * 640 + (t >> 3) * 5 + f] = f2bf(s);
        }
    }
    // zero the K-padding columns 625..639 for the 8 batch rows
    if (t < 120) {
        int b = t / 15, c = 625 + (t % 15);
        pooled[(u64)(b0 + b) * 640 + c] = 0;
    }
}

// ---------------------------------------------------------------------------
// K2: fused tail (round-7 proven). One block = 64 batch rows end-to-end:
//   z  = JKmax(BNx4(relu-chain)) of (pooled[64,640] @ fc1W^T + b)   -> LDS
//   z2 = relu(z @ lin1W^T + b1)                                    -> LDS
//   out= log_softmax(z2 @ l2W^T + b2)                              -> global
// Bs indices TILE-RELATIVE, zs ABSOLUTE (round-6 NaN bug).
// ---------------------------------------------------------------------------
__global__ __launch_bounds__(256) void k_tail(const u16* __restrict__ A,      // pooled [B,640]
                                              const u16* __restrict__ W0,     // fc1w_b [256,640]
                                              const float* __restrict__ b0v,  // fc1b
                                              const float* __restrict__ bn_a,
                                              const float* __restrict__ bn_c,
                                              const u16* __restrict__ W1,     // lin1w_b [256,256]
                                              const float* __restrict__ b1v,  // lin1b
                                              const float* __restrict__ W2,   // l2W [10,256] f32
                                              const float* __restrict__ b2v,  // l2b
                                              float* __restrict__ out) {
    __shared__ u16   As[64][72];
    __shared__ u16   Bs[256][72];
    __shared__ u16   zs[64][264];
    __shared__ float w2s[2560];
    __shared__ float b2s[10];
    int t    = threadIdx.x;
    int lane = t & 63;
    int wid  = t >> 6;
    int r0   = blockIdx.x * 64;

    for (int c = t; c < 2560; c += 256) w2s[c] = W2[c];
    if (t < 10) b2s[t] = b2v[t];

    f4v acc[16];
#pragma unroll
    for (int j = 0; j < 16; ++j) acc[j] = (f4v){0.f, 0.f, 0.f, 0.f};

    // ---------------- phase A: z = pooled @ W0^T (K=640) ----------------
    for (int k0 = 0; k0 < 640; k0 += 64) {
        int4 ra[2], rb[8];
#pragma unroll
        for (int i = 0; i < 2; ++i) {
            int c = t + i * 256, row = c >> 3, kc = c & 7;
            ra[i] = *(const int4*)(A + (u64)(r0 + row) * 640 + k0 + kc * 8);
        }
#pragma unroll
        for (int i = 0; i < 8; ++i) {
            int c = t + i * 256, row = c >> 3, kc = c & 7;
            rb[i] = *(const int4*)(W0 + (u64)row * 640 + k0 + kc * 8);
        }
        __syncthreads();
#pragma unroll
        for (int i = 0; i < 2; ++i) {
            int c = t + i * 256, row = c >> 3, kc = c & 7;
            *(int4*)(&As[row][kc * 8]) = ra[i];
        }
#pragma unroll
        for (int i = 0; i < 8; ++i) {
            int c = t + i * 256, row = c >> 3, kc = c & 7;
            *(int4*)(&Bs[row][kc * 8]) = rb[i];
        }
        __syncthreads();
#pragma unroll
        for (int ks = 0; ks < 2; ++ks) {
            int kq = ks * 32 + (lane >> 4) * 8;
            s8v af = *(const s8v*)(&As[wid * 16 + (lane & 15)][kq]);
#pragma unroll
            for (int nt = 0; nt < 16; ++nt) {
                s8v bf = *(const s8v*)(&Bs[nt * 16 + (lane & 15)][kq]);
                acc[nt] = __builtin_amdgcn_mfma_f32_16x16x32_bf16(af, bf, acc[nt], 0, 0, 0);
            }
        }
    }
#pragma unroll
    for (int nt = 0; nt < 16; ++nt) {
        int col = nt * 16 + (lane & 15);
        float bv = b0v[col];
        float a_[4], c_[4];
#pragma unroll
        for (int i = 0; i < 4; ++i) {
            a_[i] = bn_a[i * 256 + col];
            c_[i] = bn_c[i * 256 + col];
        }
        int rb_ = wid * 16 + (lane >> 4) * 4;
#pragma unroll
        for (int r = 0; r < 4; ++r) {
            float h = acc[nt][r] + bv, z = 0.0f;
#pragma unroll
            for (int i = 0; i < 4; ++i) {
                h = fmaxf(fmaf(a_[i], h, c_[i]), 0.0f);
                z = fmaxf(z, h);
            }
            zs[rb_ + r][col] = f2bf(z);
        }
    }
    __syncthreads();

    // ---------------- phase B: z2 = relu(z @ W1^T + b1) (K=256) ----------
#pragma unroll
    for (int j = 0; j < 16; ++j) acc[j] = (f4v){0.f, 0.f, 0.f, 0.f};
    for (int k0 = 0; k0 < 256; k0 += 64) {
        int4 rb[8];
#pragma unroll
        for (int i = 0; i < 8; ++i) {
            int c = t + i * 256, row = c >> 3, kc = c & 7;
            rb[i] = *(const int4*)(W1 + (u64)row * 256 + k0 + kc * 8);
        }
        __syncthreads();
#pragma unroll
        for (int i = 0; i < 8; ++i) {
            int c = t + i * 256, row = c >> 3, kc = c & 7;
            *(int4*)(&Bs[row][kc * 8]) = rb[i];
        }
        __syncthreads();
#pragma unroll
        for (int ks = 0; ks < 2; ++ks) {
            int kqr = ks * 32 + (lane >> 4) * 8;        // tile-relative: Bs
            s8v af = *(const s8v*)(&zs[wid * 16 + (lane & 15)][k0 + kqr]);  // absolute: zs
#pragma unroll
            for (int nt = 0; nt < 16; ++nt) {
                s8v bf = *(const s8v*)(&Bs[nt * 16 + (lane & 15)][kqr]);
                acc[nt] = __builtin_amdgcn_mfma_f32_16x16x32_bf16(af, bf, acc[nt], 0, 0, 0);
            }
        }
    }
#pragma unroll
    for (int nt = 0; nt < 16; ++nt) {
        int col = nt * 16 + (lane & 15);
        float bv = b1v[col];
        int rb_ = wid * 16 + (lane >> 4) * 4;
#pragma unroll
        for (int r = 0; r < 4; ++r)
            zs[rb_ + r][col] = f2bf(fmaxf(acc[nt][r] + bv, 0.0f));
    }
    __syncthreads();

    // ---------------- phase C: lin2 + log_softmax ------------------------
    {
        int row = t >> 2, sub = t & 3;
        float a10[10];
#pragma unroll
        for (int o = 0; o < 10; ++o) a10[o] = 0.0f;
        const u32* zrow = (const u32*)(&zs[row][0]);
        for (int kk = sub * 32; kk < sub * 32 + 32; ++kk) {
            u32 pz = zrow[kk];
            float z0 = bf2f((u16)(pz & 0xFFFFu));
            float z1 = bf2f((u16)(pz >> 16));
#pragma unroll
            for (int o = 0; o < 10; ++o) {
                a10[o] = fmaf(z0, w2s[o * 256 + kk * 2], a10[o]);
                a10[o] = fmaf(z1, w2s[o * 256 + kk * 2 + 1], a10[o]);
            }
        }
#pragma unroll
        for (int o = 0; o < 10; ++o) {
            a10[o] += __shfl_xor(a10[o], 1);
            a10[o] += __shfl_xor(a10[o], 2);
        }
        if (sub == 0) {
            float l[10], mx = -1e30f;
#pragma unroll
            for (int o = 0; o < 10; ++o) { l[o] = a10[o] + b2s[o]; mx = fmaxf(mx, l[o]); }
            float s = 0.0f;
#pragma unroll
            for (int o = 0; o < 10; ++o) s += expf(l[o] - mx);
            float ls = logf(s);
            float* orow = out + (u64)(r0 + row) * 10;
#pragma unroll
            for (int o = 0; o < 10; ++o) orow[o] = l[o] - mx - ls;
        }
    }
}

// ---------------------------------------------------------------------------
extern "C" void kernel_launch(void* const* d_in, const int* in_sizes, int n_in,
                              void* d_out, int out_size, void* d_ws, size_t ws_size,
                              hipStream_t stream) {
    const float* x    = (const float*)d_in[0];
    const float* L    = (const float*)d_in[1];
    const float* lmax = (const float*)d_in[2];
    const float* cl1W = (const float*)d_in[3];
    const float* cl1b = (const float*)d_in[4];
    const float* fc1W = (const float*)d_in[5];
    const float* fc1b = (const float*)d_in[6];
    const float* gam  = (const float*)d_in[7];
    const float* bet  = (const float*)d_in[8];
    const float* mea  = (const float*)d_in[9];
    const float* var  = (const float*)d_in[10];
    const float* l1W  = (const float*)d_in[11];
    const float* l1b  = (const float*)d_in[12];
    const float* l2W  = (const float*)d_in[13];
    const float* l2b  = (const float*)d_in[14];

    char* ws = (char*)d_ws;
    float* wts     = (float*)(ws + 0);        // 131072 (8*1000*4 f32)
    u16*   colsu   = (u16*)(ws + 131072);     // 65536  (8*1000*4 u16)
    int*   cnts    = (int*)(ws + 196608);     // 4096
    float* diagw   = (float*)(ws + 200704);   // 4096
    float* bn_a    = (float*)(ws + 204800);   // 4096
    float* bn_c    = (float*)(ws + 208896);   // 4096
    u16*   fc1w_b  = (u16*)(ws + 212992);     // 327680
    u16*   lin1w_b = (u16*)(ws + 540672);     // 131072
    u16*   pooled  = (u16*)(ws + 671744);     // 10485760 (total ~11.2 MB)
    float* outp    = (float*)d_out;

    k_prep<<<dim3(890), dim3(256), 0, stream>>>(L, lmax, wts, colsu, cnts, diagw,
                                                fc1W, l1W, gam, bet, mea, var,
                                                fc1w_b, lin1w_b, bn_a, bn_c);
    k_cheby<<<dim3(1024), dim3(1024), 0, stream>>>(x, (const float4*)wts,
                                                   (const uint2*)colsu, cnts, diagw,
                                                   cl1W, cl1b, pooled);
    k_tail<<<dim3(128), dim3(256), 0, stream>>>(pooled, fc1w_b, fc1b, bn_a, bn_c,
                                                lin1w_b, l1b, l2W, l2b, outp);
}

// Round 14
// 217.150 us; speedup vs baseline: 1.1614x; 1.0721x over previous
//
#include <hip/hip_runtime.h>

typedef unsigned int u32;
typedef unsigned short u16;
typedef unsigned long long u64;

typedef __attribute__((ext_vector_type(8))) short s8v;       // 8 bf16 (4 VGPRs)
typedef __attribute__((ext_vector_type(4))) float f4v;       // 4 fp32 acc
typedef __attribute__((ext_vector_type(8))) _Float16 h8v;    // 8 fp16 = 16 B

#define B_SZ   8192
#define V_SZ   1000
#define KCH    5
#define MAXDEG 32

__device__ __forceinline__ u16 f2bf(float f) {
    u32 u = __float_as_uint(f);
    u32 r = (u + 0x7FFFu + ((u >> 16) & 1u)) >> 16;   // RNE
    return (u16)r;
}
__device__ __forceinline__ float bf2f(u16 h) { return __uint_as_float(((u32)h) << 16); }
__device__ __forceinline__ float h2f(u16 h) {
    _Float16 x; __builtin_memcpy(&x, &h, 2); return (float)x;
}

// acc += w * fp16(lo/hi half of h2) in ONE v_fma_mix_f32 (r13-proven)
__device__ __forceinline__ float fmix_lo(float acc, float w, u32 h2) {
    asm("v_fma_mix_f32 %0, %1, %2, %0 op_sel_hi:[0,1,0]"
        : "+v"(acc) : "v"(w), "v"(h2));
    return acc;
}
__device__ __forceinline__ float fmix_hi(float acc, float w, u32 h2) {
    asm("v_fma_mix_f32 %0, %1, %2, %0 op_sel:[0,1,0] op_sel_hi:[0,1,0]"
        : "+v"(acc) : "v"(w), "v"(h2));
    return acc;
}

// ---------------------------------------------------------------------------
// K0: fused prep = {sparse build of Lr} U {weight bf16 conversion + BN fold}.
// blocks 0..249: build (wave-per-row scan of dense L), blocks 250..889: conv.
// Split sparse layout: wts[q4*V+v][4] fp32, colsu[q4*V+v][4] u16.
// Tails zero-padded (col 0, weight 0).
// ---------------------------------------------------------------------------
__global__ __launch_bounds__(256) void k_prep(const float* __restrict__ L,
                                              const float* __restrict__ lmax,
                                              float* __restrict__ wts,
                                              u16* __restrict__ colsu,
                                              int* __restrict__ cnts,
                                              float* __restrict__ diagw,
                                              const float* __restrict__ fc1W,
                                              const float* __restrict__ lin1W,
                                              const float* __restrict__ gam,
                                              const float* __restrict__ bet,
                                              const float* __restrict__ mea,
                                              const float* __restrict__ var,
                                              u16* __restrict__ fc1w_b,
                                              u16* __restrict__ lin1w_b,
                                              float* __restrict__ bn_a,
                                              float* __restrict__ bn_c) {
    if (blockIdx.x < 250) {
        int wid  = threadIdx.x >> 6;
        int lane = threadIdx.x & 63;
        int row  = blockIdx.x * 4 + wid;
        if (row >= V_SZ) return;
        float s = 2.0f / lmax[0];
        const float* Lrow = L + (u64)row * V_SZ;
        int cnt = 0;
        for (int c0 = 0; c0 < V_SZ; c0 += 64) {
            int c = c0 + lane;
            float val = 0.0f;
            if (c < V_SZ && c != row) val = Lrow[c];
            bool nz = (val != 0.0f);
            u64 m = __ballot(nz);
            int pos = cnt + __popcll(m & ((1ull << lane) - 1ull));
            if (nz && pos < MAXDEG) {
                int idx = ((pos >> 2) * V_SZ + row) * 4 + (pos & 3);
                wts[idx]   = val * s;
                colsu[idx] = (u16)c;
            }
            cnt += __popcll(m);
        }
        int cc = cnt < MAXDEG ? cnt : MAXDEG;
        for (int e = cc + lane; e < MAXDEG; e += 64) {
            int idx = ((e >> 2) * V_SZ + row) * 4 + (e & 3);
            wts[idx]   = 0.0f;
            colsu[idx] = 0;
        }
        if (lane == 0) {
            cnts[row]  = cc;
            diagw[row] = s * Lrow[row] - 1.0f;
        }
    } else {
        int t = (blockIdx.x - 250) * 256 + threadIdx.x;
        if (t < 256 * 640) {
            int r = t / 640, c = t - r * 640;
            fc1w_b[t] = (c < 625) ? f2bf(fc1W[r * 625 + c]) : (u16)0;
        }
        if (t < 256 * 256) lin1w_b[t] = f2bf(lin1W[t]);
        if (t < 4 * 256) {
            float a = gam[t] * rsqrtf(var[t] + 1e-5f);
            bn_a[t] = a;
            bn_c[t] = bet[t] - mea[t] * a;
        }
    }
}

// ---------------------------------------------------------------------------
// K1: fused Chebyshev recursion + cl1 + ReLU + maxpool8 -> bf16.
// 1024 thr, 8 batch cols/block, fp16 LDS stage buffers + v_fma_mix (r13).
// NEW (r14): per-block counting sort of rows by quad-count -> lanes in a wave
// have near-equal loop trip counts (divergent loop cost = wave MAX ~5.2 vs
// mean 3.3 quads). Structure loads become L2-scattered (small, prefetched);
// pooling moved to an LDS round-trip through the freed ping-pong buffer
// (u16 max is valid for relu'd fp16 >= 0).
// ---------------------------------------------------------------------------
__global__ __launch_bounds__(1024) void k_cheby(const float* __restrict__ x,
                                                const float4* __restrict__ wts4,
                                                const uint2* __restrict__ cols2,
                                                const int* __restrict__ cnts,
                                                const float* __restrict__ diagw,
                                                const float* __restrict__ cl1W,
                                                const float* __restrict__ cl1b,
                                                u16* __restrict__ pooled) {
    __shared__ __align__(16) h8v hbuf[2][V_SZ];   // pingpong, 8 cols fp16 = 32 KB
    __shared__ float cws[25];
    __shared__ float cbs[5];
    __shared__ int   hist[16];
    __shared__ u16   order[V_SZ];
    int t  = threadIdx.x;
    int b0 = blockIdx.x * 8;

    if (t < 25) cws[t] = cl1W[t];
    if (t < 5)  cbs[t] = cl1b[t];
    if (t < 16) hist[t] = 0;

    const bool own = (t < V_SZ);

    // ---- counting sort of rows by nq (9 bins) ----
    int nq_t = 0;
    if (own) nq_t = (cnts[t] + 3) >> 2;           // coalesced
    __syncthreads();
    if (own) atomicAdd(&hist[nq_t], 1);
    // ---- stage-0 staging by t (coalesced) overlaps the histogram ----
    if (own) {
        h8v hv;
        hv[0] = (_Float16)x[(u64)(b0 + 0) * V_SZ + t];
        hv[1] = (_Float16)x[(u64)(b0 + 1) * V_SZ + t];
        hv[2] = (_Float16)x[(u64)(b0 + 2) * V_SZ + t];
        hv[3] = (_Float16)x[(u64)(b0 + 3) * V_SZ + t];
        hv[4] = (_Float16)x[(u64)(b0 + 4) * V_SZ + t];
        hv[5] = (_Float16)x[(u64)(b0 + 5) * V_SZ + t];
        hv[6] = (_Float16)x[(u64)(b0 + 6) * V_SZ + t];
        hv[7] = (_Float16)x[(u64)(b0 + 7) * V_SZ + t];
        hbuf[0][t] = hv;
    }
    __syncthreads();
    if (t == 0) {
        int acc = 0;
#pragma unroll
        for (int i = 0; i < 16; ++i) { int h = hist[i]; hist[i] = acc; acc += h; }
    }
    __syncthreads();
    if (own) {
        int pos = atomicAdd(&hist[nq_t], 1);
        order[pos] = (u16)t;
    }
    __syncthreads();

    // ---- own row = order[t]; read metadata + x0 (fp16-rounded, consistent) ----
    const int r  = own ? (int)order[t] : 0;
    float d0 = 0.0f; int n0 = 0;
    float4 pm1l = make_float4(0.f, 0.f, 0.f, 0.f), pm1h = pm1l, pm2l, pm2h;
    if (own) {
        d0 = diagw[r];                            // scattered, cached
        n0 = (cnts[r] + 3) >> 2;
        h8v hv0 = hbuf[0][r];
        pm1l = make_float4((float)hv0[0], (float)hv0[1], (float)hv0[2], (float)hv0[3]);
        pm1h = make_float4((float)hv0[4], (float)hv0[5], (float)hv0[6], (float)hv0[7]);
    }
    pm2l = pm1l; pm2h = pm1h;

    // feat init with k=0 term
    float4 fl[5], fh[5];
#pragma unroll
    for (int f = 0; f < 5; ++f) {
        float w = cws[f * 5];
        fl[f] = make_float4(w * pm1l.x, w * pm1l.y, w * pm1l.z, w * pm1l.w);
        fh[f] = make_float4(w * pm1h.x, w * pm1h.y, w * pm1h.z, w * pm1h.w);
    }

    // stages 1..4
#pragma unroll
    for (int k = 1; k < KCH; ++k) {
        const uint4* prevb = (const uint4*)hbuf[(k - 1) & 1];
        h8v*         curb  = hbuf[k & 1];

        if (own) {
            float4 al = make_float4(d0 * pm1l.x, d0 * pm1l.y, d0 * pm1l.z, d0 * pm1l.w);
            float4 ah = make_float4(d0 * pm1h.x, d0 * pm1h.y, d0 * pm1h.z, d0 * pm1h.w);
            float4 wq = wts4[r];
            uint2  cq = cols2[r];
            for (int q = 0; q < n0; ++q) {
                float4 wqn = wq;
                uint2  cqn = cq;
                if (q + 1 < n0) {
                    wqn = wts4[(q + 1) * V_SZ + r];       // L2-scattered, prefetched
                    cqn = cols2[(q + 1) * V_SZ + r];
                }
                u32 c0i = cq.x & 0xFFFFu, c1i = cq.x >> 16;
                u32 c2i = cq.y & 0xFFFFu, c3i = cq.y >> 16;
                uint4 g0 = prevb[c0i];
                uint4 g1 = prevb[c1i];
                uint4 g2 = prevb[c2i];
                uint4 g3 = prevb[c3i];
                al.x = fmix_lo(al.x, wq.x, g0.x); al.y = fmix_hi(al.y, wq.x, g0.x);
                al.z = fmix_lo(al.z, wq.x, g0.y); al.w = fmix_hi(al.w, wq.x, g0.y);
                ah.x = fmix_lo(ah.x, wq.x, g0.z); ah.y = fmix_hi(ah.y, wq.x, g0.z);
                ah.z = fmix_lo(ah.z, wq.x, g0.w); ah.w = fmix_hi(ah.w, wq.x, g0.w);
                al.x = fmix_lo(al.x, wq.y, g1.x); al.y = fmix_hi(al.y, wq.y, g1.x);
                al.z = fmix_lo(al.z, wq.y, g1.y); al.w = fmix_hi(al.w, wq.y, g1.y);
                ah.x = fmix_lo(ah.x, wq.y, g1.z); ah.y = fmix_hi(ah.y, wq.y, g1.z);
                ah.z = fmix_lo(ah.z, wq.y, g1.w); ah.w = fmix_hi(ah.w, wq.y, g1.w);
                al.x = fmix_lo(al.x, wq.z, g2.x); al.y = fmix_hi(al.y, wq.z, g2.x);
                al.z = fmix_lo(al.z, wq.z, g2.y); al.w = fmix_hi(al.w, wq.z, g2.y);
                ah.x = fmix_lo(ah.x, wq.z, g2.z); ah.y = fmix_hi(ah.y, wq.z, g2.z);
                ah.z = fmix_lo(ah.z, wq.z, g2.w); ah.w = fmix_hi(ah.w, wq.z, g2.w);
                al.x = fmix_lo(al.x, wq.w, g3.x); al.y = fmix_hi(al.y, wq.w, g3.x);
                al.z = fmix_lo(al.z, wq.w, g3.y); al.w = fmix_hi(al.w, wq.w, g3.y);
                ah.x = fmix_lo(ah.x, wq.w, g3.z); ah.y = fmix_hi(ah.y, wq.w, g3.z);
                ah.z = fmix_lo(ah.z, wq.w, g3.w); ah.w = fmix_hi(ah.w, wq.w, g3.w);
                wq = wqn; cq = cqn;
            }
            if (k >= 2) {
                al.x = fmaf(2.0f, al.x, -pm2l.x); al.y = fmaf(2.0f, al.y, -pm2l.y);
                al.z = fmaf(2.0f, al.z, -pm2l.z); al.w = fmaf(2.0f, al.w, -pm2l.w);
                ah.x = fmaf(2.0f, ah.x, -pm2h.x); ah.y = fmaf(2.0f, ah.y, -pm2h.y);
                ah.z = fmaf(2.0f, ah.z, -pm2h.z); ah.w = fmaf(2.0f, ah.w, -pm2h.w);
            }
            h8v hv;
            hv[0] = (_Float16)al.x; hv[1] = (_Float16)al.y;
            hv[2] = (_Float16)al.z; hv[3] = (_Float16)al.w;
            hv[4] = (_Float16)ah.x; hv[5] = (_Float16)ah.y;
            hv[6] = (_Float16)ah.z; hv[7] = (_Float16)ah.w;
            curb[r] = hv;                         // scattered write (perm: unique r)
            pm2l = pm1l; pm2h = pm1h;
            pm1l = al;   pm1h = ah;
#pragma unroll
            for (int f = 0; f < 5; ++f) {
                float w = cws[f * 5 + k];
                fl[f].x = fmaf(w, al.x, fl[f].x); fl[f].y = fmaf(w, al.y, fl[f].y);
                fl[f].z = fmaf(w, al.z, fl[f].z); fl[f].w = fmaf(w, al.w, fl[f].w);
                fh[f].x = fmaf(w, ah.x, fh[f].x); fh[f].y = fmaf(w, ah.y, fh[f].y);
                fh[f].z = fmaf(w, ah.z, fh[f].z); fh[f].w = fmaf(w, ah.w, fh[f].w);
            }
        }
        __syncthreads();
    }

    // ---- bias + ReLU + maxpool8 via LDS scratch (hbuf[1] free: stage 4
    // wrote hbuf[0]). u16 compare == fp16 max for relu'd (>=0) values. ----
    for (int f = 0; f < 5; ++f) {
        if (own) {
            h8v hv;
            hv[0] = (_Float16)fmaxf(fl[f].x + cbs[f], 0.0f);
            hv[1] = (_Float16)fmaxf(fl[f].y + cbs[f], 0.0f);
            hv[2] = (_Float16)fmaxf(fl[f].z + cbs[f], 0.0f);
            hv[3] = (_Float16)fmaxf(fl[f].w + cbs[f], 0.0f);
            hv[4] = (_Float16)fmaxf(fh[f].x + cbs[f], 0.0f);
            hv[5] = (_Float16)fmaxf(fh[f].y + cbs[f], 0.0f);
            hv[6] = (_Float16)fmaxf(fh[f].z + cbs[f], 0.0f);
            hv[7] = (_Float16)fmaxf(fh[f].w + cbs[f], 0.0f);
            hbuf[1][r] = hv;
        }
        __syncthreads();
        if (own) {
            int p = t >> 3, b = t & 7;            // 125 pools x 8 batch cols
            const u16* sc = (const u16*)hbuf[1];
            u16 m = 0;
#pragma unroll
            for (int j = 0; j < 8; ++j) {
                u16 v = sc[(8 * p + j) * 8 + b];
                m = (v > m) ? v : m;
            }
            pooled[(u64)(b0 + b) * 640 + p * 5 + f] = f2bf(h2f(m));
        }
        __syncthreads();
    }
    // zero the K-padding columns 625..639 for the 8 batch rows
    if (t < 120) {
        int b = t / 15, c = 625 + (t % 15);
        pooled[(u64)(b0 + b) * 640 + c] = 0;
    }
}

// ---------------------------------------------------------------------------
// K2: fused tail (round-7 proven). One block = 64 batch rows end-to-end:
//   z  = JKmax(BNx4(relu-chain)) of (pooled[64,640] @ fc1W^T + b)   -> LDS
//   z2 = relu(z @ lin1W^T + b1)                                    -> LDS
//   out= log_softmax(z2 @ l2W^T + b2)                              -> global
// Bs indices TILE-RELATIVE, zs ABSOLUTE (round-6 NaN bug).
// ---------------------------------------------------------------------------
__global__ __launch_bounds__(256) void k_tail(const u16* __restrict__ A,      // pooled [B,640]
                                              const u16* __restrict__ W0,     // fc1w_b [256,640]
                                              const float* __restrict__ b0v,  // fc1b
                                              const float* __restrict__ bn_a,
                                              const float* __restrict__ bn_c,
                                              const u16* __restrict__ W1,     // lin1w_b [256,256]
                                              const float* __restrict__ b1v,  // lin1b
                                              const float* __restrict__ W2,   // l2W [10,256] f32
                                              const float* __restrict__ b2v,  // l2b
                                              float* __restrict__ out) {
    __shared__ u16   As[64][72];
    __shared__ u16   Bs[256][72];
    __shared__ u16   zs[64][264];
    __shared__ float w2s[2560];
    __shared__ float b2s[10];
    int t    = threadIdx.x;
    int lane = t & 63;
    int wid  = t >> 6;
    int r0   = blockIdx.x * 64;

    for (int c = t; c < 2560; c += 256) w2s[c] = W2[c];
    if (t < 10) b2s[t] = b2v[t];

    f4v acc[16];
#pragma unroll
    for (int j = 0; j < 16; ++j) acc[j] = (f4v){0.f, 0.f, 0.f, 0.f};

    // ---------------- phase A: z = pooled @ W0^T (K=640) ----------------
    for (int k0 = 0; k0 < 640; k0 += 64) {
        int4 ra[2], rb[8];
#pragma unroll
        for (int i = 0; i < 2; ++i) {
            int c = t + i * 256, row = c >> 3, kc = c & 7;
            ra[i] = *(const int4*)(A + (u64)(r0 + row) * 640 + k0 + kc * 8);
        }
#pragma unroll
        for (int i = 0; i < 8; ++i) {
            int c = t + i * 256, row = c >> 3, kc = c & 7;
            rb[i] = *(const int4*)(W0 + (u64)row * 640 + k0 + kc * 8);
        }
        __syncthreads();
#pragma unroll
        for (int i = 0; i < 2; ++i) {
            int c = t + i * 256, row = c >> 3, kc = c & 7;
            *(int4*)(&As[row][kc * 8]) = ra[i];
        }
#pragma unroll
        for (int i = 0; i < 8; ++i) {
            int c = t + i * 256, row = c >> 3, kc = c & 7;
            *(int4*)(&Bs[row][kc * 8]) = rb[i];
        }
        __syncthreads();
#pragma unroll
        for (int ks = 0; ks < 2; ++ks) {
            int kq = ks * 32 + (lane >> 4) * 8;
            s8v af = *(const s8v*)(&As[wid * 16 + (lane & 15)][kq]);
#pragma unroll
            for (int nt = 0; nt < 16; ++nt) {
                s8v bf = *(const s8v*)(&Bs[nt * 16 + (lane & 15)][kq]);
                acc[nt] = __builtin_amdgcn_mfma_f32_16x16x32_bf16(af, bf, acc[nt], 0, 0, 0);
            }
        }
    }
#pragma unroll
    for (int nt = 0; nt < 16; ++nt) {
        int col = nt * 16 + (lane & 15);
        float bv = b0v[col];
        float a_[4], c_[4];
#pragma unroll
        for (int i = 0; i < 4; ++i) {
            a_[i] = bn_a[i * 256 + col];
            c_[i] = bn_c[i * 256 + col];
        }
        int rb_ = wid * 16 + (lane >> 4) * 4;
#pragma unroll
        for (int r = 0; r < 4; ++r) {
            float h = acc[nt][r] + bv, z = 0.0f;
#pragma unroll
            for (int i = 0; i < 4; ++i) {
                h = fmaxf(fmaf(a_[i], h, c_[i]), 0.0f);
                z = fmaxf(z, h);
            }
            zs[rb_ + r][col] = f2bf(z);
        }
    }
    __syncthreads();

    // ---------------- phase B: z2 = relu(z @ W1^T + b1) (K=256) ----------
#pragma unroll
    for (int j = 0; j < 16; ++j) acc[j] = (f4v){0.f, 0.f, 0.f, 0.f};
    for (int k0 = 0; k0 < 256; k0 += 64) {
        int4 rb[8];
#pragma unroll
        for (int i = 0; i < 8; ++i) {
            int c = t + i * 256, row = c >> 3, kc = c & 7;
            rb[i] = *(const int4*)(W1 + (u64)row * 256 + k0 + kc * 8);
        }
        __syncthreads();
#pragma unroll
        for (int i = 0; i < 8; ++i) {
            int c = t + i * 256, row = c >> 3, kc = c & 7;
            *(int4*)(&Bs[row][kc * 8]) = rb[i];
        }
        __syncthreads();
#pragma unroll
        for (int ks = 0; ks < 2; ++ks) {
            int kqr = ks * 32 + (lane >> 4) * 8;        // tile-relative: Bs
            s8v af = *(const s8v*)(&zs[wid * 16 + (lane & 15)][k0 + kqr]);  // absolute: zs
#pragma unroll
            for (int nt = 0; nt < 16; ++nt) {
                s8v bf = *(const s8v*)(&Bs[nt * 16 + (lane & 15)][kqr]);
                acc[nt] = __builtin_amdgcn_mfma_f32_16x16x32_bf16(af, bf, acc[nt], 0, 0, 0);
            }
        }
    }
#pragma unroll
    for (int nt = 0; nt < 16; ++nt) {
        int col = nt * 16 + (lane & 15);
        float bv = b1v[col];
        int rb_ = wid * 16 + (lane >> 4) * 4;
#pragma unroll
        for (int r = 0; r < 4; ++r)
            zs[rb_ + r][col] = f2bf(fmaxf(acc[nt][r] + bv, 0.0f));
    }
    __syncthreads();

    // ---------------- phase C: lin2 + log_softmax ------------------------
    {
        int row = t >> 2, sub = t & 3;
        float a10[10];
#pragma unroll
        for (int o = 0; o < 10; ++o) a10[o] = 0.0f;
        const u32* zrow = (const u32*)(&zs[row][0]);
        for (int kk = sub * 32; kk < sub * 32 + 32; ++kk) {
            u32 pz = zrow[kk];
            float z0 = bf2f((u16)(pz & 0xFFFFu));
            float z1 = bf2f((u16)(pz >> 16));
#pragma unroll
            for (int o = 0; o < 10; ++o) {
                a10[o] = fmaf(z0, w2s[o * 256 + kk * 2], a10[o]);
                a10[o] = fmaf(z1, w2s[o * 256 + kk * 2 + 1], a10[o]);
            }
        }
#pragma unroll
        for (int o = 0; o < 10; ++o) {
            a10[o] += __shfl_xor(a10[o], 1);
            a10[o] += __shfl_xor(a10[o], 2);
        }
        if (sub == 0) {
            float l[10], mx = -1e30f;
#pragma unroll
            for (int o = 0; o < 10; ++o) { l[o] = a10[o] + b2s[o]; mx = fmaxf(mx, l[o]); }
            float s = 0.0f;
#pragma unroll
            for (int o = 0; o < 10; ++o) s += expf(l[o] - mx);
            float ls = logf(s);
            float* orow = out + (u64)(r0 + row) * 10;
#pragma unroll
            for (int o = 0; o < 10; ++o) orow[o] = l[o] - mx - ls;
        }
    }
}

// ---------------------------------------------------------------------------
extern "C" void kernel_launch(void* const* d_in, const int* in_sizes, int n_in,
                              void* d_out, int out_size, void* d_ws, size_t ws_size,
                              hipStream_t stream) {
    const float* x    = (const float*)d_in[0];
    const float* L    = (const float*)d_in[1];
    const float* lmax = (const float*)d_in[2];
    const float* cl1W = (const float*)d_in[3];
    const float* cl1b = (const float*)d_in[4];
    const float* fc1W = (const float*)d_in[5];
    const float* fc1b = (const float*)d_in[6];
    const float* gam  = (const float*)d_in[7];
    const float* bet  = (const float*)d_in[8];
    const float* mea  = (const float*)d_in[9];
    const float* var  = (const float*)d_in[10];
    const float* l1W  = (const float*)d_in[11];
    const float* l1b  = (const float*)d_in[12];
    const float* l2W  = (const float*)d_in[13];
    const float* l2b  = (const float*)d_in[14];

    char* ws = (char*)d_ws;
    float* wts     = (float*)(ws + 0);        // 131072 (8*1000*4 f32)
    u16*   colsu   = (u16*)(ws + 131072);     // 65536  (8*1000*4 u16)
    int*   cnts    = (int*)(ws + 196608);     // 4096
    float* diagw   = (float*)(ws + 200704);   // 4096
    float* bn_a    = (float*)(ws + 204800);   // 4096
    float* bn_c    = (float*)(ws + 208896);   // 4096
    u16*   fc1w_b  = (u16*)(ws + 212992);     // 327680
    u16*   lin1w_b = (u16*)(ws + 540672);     // 131072
    u16*   pooled  = (u16*)(ws + 671744);     // 10485760 (total ~11.2 MB)
    float* outp    = (float*)d_out;

    k_prep<<<dim3(890), dim3(256), 0, stream>>>(L, lmax, wts, colsu, cnts, diagw,
                                                fc1W, l1W, gam, bet, mea, var,
                                                fc1w_b, lin1w_b, bn_a, bn_c);
    k_cheby<<<dim3(1024), dim3(1024), 0, stream>>>(x, (const float4*)wts,
                                                   (const uint2*)colsu, cnts, diagw,
                                                   cl1W, cl1b, pooled);
    k_tail<<<dim3(128), dim3(256), 0, stream>>>(pooled, fc1w_b, fc1b, bn_a, bn_c,
                                                lin1w_b, l1b, l2W, l2b, outp);
}